// Round 1
// baseline (603.450 us; speedup 1.0000x reference)
//
#include <hip/hip_runtime.h>

// MeanAggregator: out[b][:] = mean_{s<10} features[neigh_idx[b][s]][:]
// B=50000, S=10, N=1e6, D=128, fp32. Purely memory-bound gather+mean.
//
// Layout: 32 lanes per output row, each lane owns one float4 chunk (D=128 =
// 32 * float4). A chunk-group's 32 lanes read 512 contiguous bytes = one full
// feature row -> perfectly coalesced. S=10 loop fully unrolled for MLP.

constexpr int D      = 128;
constexpr int CHUNKS = D / 4;   // 32 lanes per row
constexpr int S      = 10;      // num_sample (fixed in reference)

__global__ __launch_bounds__(256)
void mean_agg_kernel(const int* __restrict__ idx,
                     const float* __restrict__ feat,
                     float* __restrict__ out,
                     int B)
{
    const int tid = blockIdx.x * blockDim.x + threadIdx.x;
    const int row = tid >> 5;          // tid / CHUNKS
    const int c   = tid & 31;          // tid % CHUNKS
    if (row >= B) return;

    const int* ib = idx + (long)row * S;

    // Load all 10 indices first so the 10 gather loads can issue back-to-back.
    int r[S];
#pragma unroll
    for (int s = 0; s < S; ++s) r[s] = ib[s];

    float4 acc = make_float4(0.f, 0.f, 0.f, 0.f);
#pragma unroll
    for (int s = 0; s < S; ++s) {
        const float4 v = *(const float4*)(feat + (long)r[s] * D + c * 4);
        acc.x += v.x; acc.y += v.y; acc.z += v.z; acc.w += v.w;
    }

    constexpr float invS = 1.0f / S;
    acc.x *= invS; acc.y *= invS; acc.z *= invS; acc.w *= invS;

    *(float4*)(out + (long)row * D + c * 4) = acc;
}

extern "C" void kernel_launch(void* const* d_in, const int* in_sizes, int n_in,
                              void* d_out, int out_size, void* d_ws, size_t ws_size,
                              hipStream_t stream) {
    const int*   idx  = (const int*)d_in[0];    // [B, S] int
    const float* feat = (const float*)d_in[1];  // [N, D] fp32
    float*       out  = (float*)d_out;          // [B, D] fp32

    const int B = out_size / D;                 // 50000

    const int threads = 256;
    const int total   = B * CHUNKS;             // one thread per float4 chunk
    const int blocks  = (total + threads - 1) / threads;

    mean_agg_kernel<<<blocks, threads, 0, stream>>>(idx, feat, out, B);
}

// Round 3
// 591.002 us; speedup vs baseline: 1.0211x; 1.0211x over previous
//
#include <hip/hip_runtime.h>

// MeanAggregator: out[b][:] = mean_{s<10} features[neigh_idx[b][s]][:]
// B=50000, S=10, N=1e6, D=128, fp32. Latency-bound random gather.
//
// Round-3 = round-2 with the compile fix: __builtin_nontemporal_store needs a
// native clang vector type, not HIP_vector_type<float,4>. Use
// ext_vector_type(4) throughout.
//
// Experiment: 2 output rows per thread, all 20 float4 gathers issued into a
// register array before any accumulation -> 20 global_load_dwordx4 in flight
// per lane (vs 10), half as many waitcnt drain points per wave.
// __launch_bounds__(256,4): keep VGPR <= 128 so 4 waves/SIMD stay resident.
// Nontemporal output stores: out rows are never re-read; keep LLC lines for
// feature-row duplicates (~21% of the 500K sampled rows are dups).

typedef float v4f __attribute__((ext_vector_type(4)));

constexpr int D      = 128;
constexpr int CHUNKS = D / 4;   // 32 lanes per row (float4 chunks)
constexpr int S      = 10;      // num_sample (fixed in reference)

__global__ __launch_bounds__(256, 4)
void mean_agg_kernel(const int* __restrict__ idx,
                     const float* __restrict__ feat,
                     float* __restrict__ out,
                     int halfB)
{
    const int tid  = blockIdx.x * blockDim.x + threadIdx.x;
    const int c    = tid & 31;         // float4 chunk within row
    const int pair = tid >> 5;         // which row-pair
    if (pair >= halfB) return;

    const int row0 = pair;
    const int row1 = pair + halfB;

    const int* i0 = idx + (long)row0 * S;
    const int* i1 = idx + (long)row1 * S;

    // All 20 indices first (sequential, L1/L2-resident after first touch).
    int r[2 * S];
#pragma unroll
    for (int s = 0; s < S; ++s) { r[s] = i0[s]; r[S + s] = i1[s]; }

    // Issue all 20 gathers before consuming any -> max per-lane MLP.
    const float* base = feat + c * 4;
    v4f v[2 * S];
#pragma unroll
    for (int s = 0; s < 2 * S; ++s) {
        v[s] = *(const v4f*)(base + (long)r[s] * D);
    }

    v4f a0 = (v4f)(0.f);
    v4f a1 = (v4f)(0.f);
#pragma unroll
    for (int s = 0; s < S; ++s) {
        a0 += v[s];
        a1 += v[S + s];
    }

    constexpr float invS = 1.0f / S;
    a0 *= invS;
    a1 *= invS;

    __builtin_nontemporal_store(a0, (v4f*)(out + (long)row0 * D + c * 4));
    __builtin_nontemporal_store(a1, (v4f*)(out + (long)row1 * D + c * 4));
}

extern "C" void kernel_launch(void* const* d_in, const int* in_sizes, int n_in,
                              void* d_out, int out_size, void* d_ws, size_t ws_size,
                              hipStream_t stream) {
    const int*   idx  = (const int*)d_in[0];    // [B, S] int
    const float* feat = (const float*)d_in[1];  // [N, D] fp32
    float*       out  = (float*)d_out;          // [B, D] fp32

    const int B     = out_size / D;             // 50000
    const int halfB = B / 2;                    // 25000 (B is even)

    const int threads = 256;
    const int total   = halfB * CHUNKS;         // one thread per 2 rows x chunk
    const int blocks  = (total + threads - 1) / threads;

    mean_agg_kernel<<<blocks, threads, 0, stream>>>(idx, feat, out, halfB);
}